// Round 4
// baseline (116.652 us; speedup 1.0000x reference)
//
#include <hip/hip_runtime.h>

#define HIDDEN 128

typedef float v4f __attribute__((ext_vector_type(4)));

__device__ __forceinline__ float dot4(const v4f a, const v4f b) {
    return a.x * b.x + a.y * b.y + a.z * b.z + a.w * b.w;
}

// Phase 1: ns[n] = dot(node[n], W[128:256]); nd[n] = dot(node[n], W[256:384]).
// 8 lanes per node, 16 floats (4x v4f) per lane, 3-step shuffle reduce.
// Grid-stride so the W chunks stay in registers.
__global__ __launch_bounds__(256)
void node_dots_kernel(const float* __restrict__ node_hidden,
                      const float* __restrict__ W,   // [384]
                      float* __restrict__ ns,        // [n_nodes]
                      float* __restrict__ nd,        // [n_nodes]
                      int n_nodes) {
    const int h       = threadIdx.x & 7;                                  // lane within node-group
    const int slot    = (blockIdx.x * blockDim.x + threadIdx.x) >> 3;
    const int n_slots = (gridDim.x * blockDim.x) >> 3;

    const v4f* Wsv = reinterpret_cast<const v4f*>(W + HIDDEN) + h * 4;
    const v4f* Wdv = reinterpret_cast<const v4f*>(W + 2 * HIDDEN) + h * 4;
    const v4f ws0 = Wsv[0], ws1 = Wsv[1], ws2 = Wsv[2], ws3 = Wsv[3];
    const v4f wd0 = Wdv[0], wd1 = Wdv[1], wd2 = Wdv[2], wd3 = Wdv[3];

    for (int n = slot; n < n_nodes; n += n_slots) {
        const v4f* row = reinterpret_cast<const v4f*>(node_hidden + (size_t)n * HIDDEN) + h * 4;
        const v4f x0 = __builtin_nontemporal_load(row + 0);
        const v4f x1 = __builtin_nontemporal_load(row + 1);
        const v4f x2 = __builtin_nontemporal_load(row + 2);
        const v4f x3 = __builtin_nontemporal_load(row + 3);

        float as = dot4(x0, ws0) + dot4(x1, ws1) + dot4(x2, ws2) + dot4(x3, ws3);
        float ad = dot4(x0, wd0) + dot4(x1, wd1) + dot4(x2, wd2) + dot4(x3, wd3);

        as += __shfl_down(as, 4, 8);
        as += __shfl_down(as, 2, 8);
        as += __shfl_down(as, 1, 8);
        ad += __shfl_down(ad, 4, 8);
        ad += __shfl_down(ad, 2, 8);
        ad += __shfl_down(ad, 1, 8);

        if (h == 0) {
            ns[n] = as;
            nd[n] = ad;
        }
    }
}

// Phase 2: out[e] = dot(edge_hidden[e], W[0:128]) + ns[src] + nd[dst] + b.
// 8 lanes per edge, 64 B per lane, grid-stride. ns/nd (800 KB) stay L2-hot;
// edge_hidden is nontemporal-streamed so it doesn't evict them.
__global__ __launch_bounds__(256)
void edge_out_kernel(const float* __restrict__ edge_hidden,
                     const int*   __restrict__ edge_index, // [2][n_edges]
                     const float* __restrict__ W,          // [384]
                     const float* __restrict__ b,          // [1]
                     const float* __restrict__ ns,
                     const float* __restrict__ nd,
                     float* __restrict__ out,
                     int n_edges) {
    const int h       = threadIdx.x & 7;
    const int slot    = (blockIdx.x * blockDim.x + threadIdx.x) >> 3;
    const int n_slots = (gridDim.x * blockDim.x) >> 3;

    const v4f* Wev = reinterpret_cast<const v4f*>(W) + h * 4;
    const v4f we0 = Wev[0], we1 = Wev[1], we2 = Wev[2], we3 = Wev[3];
    const float bias = b[0];

    for (int e = slot; e < n_edges; e += n_slots) {
        const v4f* row = reinterpret_cast<const v4f*>(edge_hidden + (size_t)e * HIDDEN) + h * 4;
        const v4f x0 = __builtin_nontemporal_load(row + 0);
        const v4f x1 = __builtin_nontemporal_load(row + 1);
        const v4f x2 = __builtin_nontemporal_load(row + 2);
        const v4f x3 = __builtin_nontemporal_load(row + 3);

        float acc = dot4(x0, we0) + dot4(x1, we1) + dot4(x2, we2) + dot4(x3, we3);

        acc += __shfl_down(acc, 4, 8);
        acc += __shfl_down(acc, 2, 8);
        acc += __shfl_down(acc, 1, 8);

        if (h == 0) {
            const int s = edge_index[e];
            const int d = edge_index[n_edges + e];
            out[e] = acc + ns[s] + nd[d] + bias;
        }
    }
}

extern "C" void kernel_launch(void* const* d_in, const int* in_sizes, int n_in,
                              void* d_out, int out_size, void* d_ws, size_t ws_size,
                              hipStream_t stream) {
    const float* node_hidden = (const float*)d_in[0];
    const float* edge_hidden = (const float*)d_in[1];
    const int*   edge_index  = (const int*)d_in[2];
    const float* W           = (const float*)d_in[3];
    const float* b           = (const float*)d_in[4];
    float* out = (float*)d_out;

    const int n_nodes = in_sizes[0] / HIDDEN;
    const int n_edges = in_sizes[2] / 2;

    float* ns = (float*)d_ws;
    float* nd = ns + n_nodes;

    {
        const int threads = 256;
        int blocks = (n_nodes * 8 + threads - 1) / threads;
        if (blocks > 2048) blocks = 2048;
        node_dots_kernel<<<blocks, threads, 0, stream>>>(node_hidden, W, ns, nd, n_nodes);
    }
    {
        const int threads = 256;
        int blocks = (n_edges * 8 + threads - 1) / threads;
        if (blocks > 2048) blocks = 2048;
        edge_out_kernel<<<blocks, threads, 0, stream>>>(edge_hidden, edge_index, W, b,
                                                        ns, nd, out, n_edges);
    }
}

// Round 5
// 79.914 us; speedup vs baseline: 1.4597x; 1.4597x over previous
//
#include <hip/hip_runtime.h>

#define HIDDEN 128

typedef float v4f __attribute__((ext_vector_type(4)));

__device__ __forceinline__ float dot4(const v4f a, const v4f b) {
    return a.x * b.x + a.y * b.y + a.z * b.z + a.w * b.w;
}

// Phase 1: ns[n] = dot(node[n], W[128:256]); nd[n] = dot(node[n], W[256:384]).
// 32 lanes per node, one float4 per lane (512B contiguous per group), 5-step
// dual shuffle reduce. (Proven R2 pattern, plain loads.)
__global__ __launch_bounds__(256)
void node_dots_kernel(const float* __restrict__ node_hidden,
                      const float* __restrict__ W,   // [384]
                      float* __restrict__ ns,        // [n_nodes]
                      float* __restrict__ nd,        // [n_nodes]
                      int n_nodes) {
    const int tid  = blockIdx.x * blockDim.x + threadIdx.x;
    const int node = tid >> 5;
    const int lane = tid & 31;
    if (node >= n_nodes) return;

    const v4f v  = reinterpret_cast<const v4f*>(node_hidden + (size_t)node * HIDDEN)[lane];
    const v4f ws = reinterpret_cast<const v4f*>(W + HIDDEN)[lane];
    const v4f wd = reinterpret_cast<const v4f*>(W + 2 * HIDDEN)[lane];

    float as = dot4(v, ws);
    float ad = dot4(v, wd);

    #pragma unroll
    for (int off = 16; off > 0; off >>= 1) {
        as += __shfl_down(as, off, 32);
        ad += __shfl_down(ad, off, 32);
    }
    if (lane == 0) {
        ns[node] = as;
        nd[node] = ad;
    }
}

// Phase 2: out[e] = ns[src[e]] + nd[dst[e]] + b. One edge per lane: coalesced
// index reads, 64 independent gathers in flight per wave (table is 800 KB,
// L2/L3 resident), coalesced out writes. Removes the lane-0 serial gather
// chain from the streaming kernel.
__global__ __launch_bounds__(256)
void gather_base_kernel(const int* __restrict__ edge_index, // [2][n_edges]
                        const float* __restrict__ ns,
                        const float* __restrict__ nd,
                        const float* __restrict__ b,
                        float* __restrict__ out,
                        int n_edges) {
    const int e = blockIdx.x * blockDim.x + threadIdx.x;
    if (e >= n_edges) return;
    const int s = edge_index[e];
    const int d = edge_index[n_edges + e];
    out[e] = ns[s] + nd[d] + b[0];
}

// Phase 3: out[e] += dot(edge_hidden[e], W[0:128]).
// 32 lanes per edge, 4 edges per group (4 independent loads in flight,
// 4 interleaved shuffle-reduce chains). Per instruction each group reads a
// fully contiguous 512 B row segment. Lane 0 does a single 16 B RMW.
__global__ __launch_bounds__(256)
void edge_dot_kernel(const float* __restrict__ edge_hidden,
                     const float* __restrict__ W,   // [384]
                     float* __restrict__ out,
                     int n_edges) {
    const int tid  = blockIdx.x * blockDim.x + threadIdx.x;
    const int grp  = tid >> 5;
    const int lane = tid & 31;
    const int e0   = grp * 4;
    if (e0 >= n_edges) return;

    const v4f we = reinterpret_cast<const v4f*>(W)[lane];

    const v4f* r = reinterpret_cast<const v4f*>(edge_hidden) + (size_t)e0 * 32 + lane;
    const v4f x0 = r[0];
    const v4f x1 = r[32];
    const v4f x2 = r[64];
    const v4f x3 = r[96];

    float a0 = dot4(x0, we);
    float a1 = dot4(x1, we);
    float a2 = dot4(x2, we);
    float a3 = dot4(x3, we);

    #pragma unroll
    for (int off = 16; off > 0; off >>= 1) {
        a0 += __shfl_down(a0, off, 32);
        a1 += __shfl_down(a1, off, 32);
        a2 += __shfl_down(a2, off, 32);
        a3 += __shfl_down(a3, off, 32);
    }

    if (lane == 0) {
        v4f* o4 = reinterpret_cast<v4f*>(out + e0);
        v4f o = *o4;
        o.x += a0; o.y += a1; o.z += a2; o.w += a3;
        *o4 = o;
    }
}

extern "C" void kernel_launch(void* const* d_in, const int* in_sizes, int n_in,
                              void* d_out, int out_size, void* d_ws, size_t ws_size,
                              hipStream_t stream) {
    const float* node_hidden = (const float*)d_in[0];
    const float* edge_hidden = (const float*)d_in[1];
    const int*   edge_index  = (const int*)d_in[2];
    const float* W           = (const float*)d_in[3];
    const float* b           = (const float*)d_in[4];
    float* out = (float*)d_out;

    const int n_nodes = in_sizes[0] / HIDDEN;
    const int n_edges = in_sizes[2] / 2;

    float* ns = (float*)d_ws;
    float* nd = ns + n_nodes;

    {
        const int threads = 256;
        const int blocks = (n_nodes * 32 + threads - 1) / threads;
        node_dots_kernel<<<blocks, threads, 0, stream>>>(node_hidden, W, ns, nd, n_nodes);
    }
    {
        const int threads = 256;
        const int blocks = (n_edges + threads - 1) / threads;
        gather_base_kernel<<<blocks, threads, 0, stream>>>(edge_index, ns, nd, b, out, n_edges);
    }
    {
        const int threads = 256;
        const int groups  = (n_edges + 3) / 4;                 // 4 edges per 32-lane group
        const int blocks  = (groups * 32 + threads - 1) / threads;
        edge_dot_kernel<<<blocks, threads, 0, stream>>>(edge_hidden, W, out, n_edges);
    }
}

// Round 6
// 70.604 us; speedup vs baseline: 1.6522x; 1.1319x over previous
//
#include <hip/hip_runtime.h>

#define HIDDEN 128

typedef float v4f __attribute__((ext_vector_type(4)));

__device__ __forceinline__ float dot4(const v4f a, const v4f b) {
    return a.x * b.x + a.y * b.y + a.z * b.z + a.w * b.w;
}

// Phase 1: ns[n] = dot(node[n], W[128:256]); nd[n] = dot(node[n], W[256:384]).
// 32 lanes per node, one float4 per lane (512B contiguous per group), 5-step
// dual shuffle reduce.
__global__ __launch_bounds__(256)
void node_dots_kernel(const float* __restrict__ node_hidden,
                      const float* __restrict__ W,   // [384]
                      float* __restrict__ ns,        // [n_nodes]
                      float* __restrict__ nd,        // [n_nodes]
                      int n_nodes) {
    const int tid  = blockIdx.x * blockDim.x + threadIdx.x;
    const int node = tid >> 5;
    const int lane = tid & 31;
    if (node >= n_nodes) return;

    const v4f v  = reinterpret_cast<const v4f*>(node_hidden + (size_t)node * HIDDEN)[lane];
    const v4f ws = reinterpret_cast<const v4f*>(W + HIDDEN)[lane];
    const v4f wd = reinterpret_cast<const v4f*>(W + 2 * HIDDEN)[lane];

    float as = dot4(v, ws);
    float ad = dot4(v, wd);

    #pragma unroll
    for (int off = 16; off > 0; off >>= 1) {
        as += __shfl_down(as, off, 32);
        ad += __shfl_down(ad, off, 32);
    }
    if (lane == 0) {
        ns[node] = as;
        nd[node] = ad;
    }
}

// Phase 2 (fused): out[e] = dot(edge_hidden[e], W[0:128]) + ns[src] + nd[dst] + b.
// 4 edges per 32-lane group. Lanes 0-3 each own one edge's gather chain
// (index load -> 800KB L2-resident table gather), issued BEFORE the stream
// loads so the gather latency hides under the dots. Butterfly reduce puts all
// four sums on every lane; lanes 0-3 write 4 contiguous floats.
__global__ __launch_bounds__(256)
void edge_fused_kernel(const float* __restrict__ edge_hidden,
                       const int*   __restrict__ edge_index, // [2][n_edges]
                       const float* __restrict__ W,          // [384]
                       const float* __restrict__ b,          // [1]
                       const float* __restrict__ ns,
                       const float* __restrict__ nd,
                       float* __restrict__ out,
                       int n_edges) {
    const int tid  = blockIdx.x * blockDim.x + threadIdx.x;
    const int grp  = tid >> 5;
    const int lane = tid & 31;
    const int e0   = grp * 4;
    if (e0 >= n_edges) return;

    // per-lane epilogue gather (lanes 0-3), overlapped with the stream below
    float base = 0.0f;
    const int my_e = e0 + lane;
    if (lane < 4 && my_e < n_edges) {
        const int s = edge_index[my_e];
        const int d = edge_index[n_edges + my_e];
        base = ns[s] + nd[d] + b[0];
    }

    const v4f we = reinterpret_cast<const v4f*>(W)[lane];
    const v4f* r = reinterpret_cast<const v4f*>(edge_hidden) + (size_t)e0 * 32 + lane;
    const v4f x0 = r[0];
    const v4f x1 = r[32];
    const v4f x2 = r[64];
    const v4f x3 = r[96];

    float a0 = dot4(x0, we);
    float a1 = dot4(x1, we);
    float a2 = dot4(x2, we);
    float a3 = dot4(x3, we);

    #pragma unroll
    for (int off = 16; off > 0; off >>= 1) {
        a0 += __shfl_xor(a0, off, 32);
        a1 += __shfl_xor(a1, off, 32);
        a2 += __shfl_xor(a2, off, 32);
        a3 += __shfl_xor(a3, off, 32);
    }

    if (lane < 4 && my_e < n_edges) {
        const float a = (lane == 0) ? a0 : (lane == 1) ? a1 : (lane == 2) ? a2 : a3;
        out[my_e] = a + base;
    }
}

extern "C" void kernel_launch(void* const* d_in, const int* in_sizes, int n_in,
                              void* d_out, int out_size, void* d_ws, size_t ws_size,
                              hipStream_t stream) {
    const float* node_hidden = (const float*)d_in[0];
    const float* edge_hidden = (const float*)d_in[1];
    const int*   edge_index  = (const int*)d_in[2];
    const float* W           = (const float*)d_in[3];
    const float* b           = (const float*)d_in[4];
    float* out = (float*)d_out;

    const int n_nodes = in_sizes[0] / HIDDEN;
    const int n_edges = in_sizes[2] / 2;

    float* ns = (float*)d_ws;
    float* nd = ns + n_nodes;

    {
        const int threads = 256;
        const int blocks = (n_nodes * 32 + threads - 1) / threads;
        node_dots_kernel<<<blocks, threads, 0, stream>>>(node_hidden, W, ns, nd, n_nodes);
    }
    {
        const int threads = 256;
        const int groups  = (n_edges + 3) / 4;                 // 4 edges per 32-lane group
        const int blocks  = (groups * 32 + threads - 1) / threads;
        edge_fused_kernel<<<blocks, threads, 0, stream>>>(edge_hidden, edge_index, W, b,
                                                          ns, nd, out, n_edges);
    }
}